// Round 3
// baseline (181.341 us; speedup 1.0000x reference)
//
#include <hip/hip_runtime.h>
#include <hip/hip_bf16.h>

#define NN 32
#define CIN 64
#define TTOT 300
#define VV 25
#define PP 3
#define COUT 128
#define TTILE 5
#define NTILES 60
#define CNT 240000.0f

#define XSTR 40      // X/At w-stride in shorts: 80B rows -> 2-way banks, 16B aligned
#define ZSTR 72      // Z2 c-stride in shorts: 144B rows -> ~2-way on b128 reads
#define ZROWS 128    // 125 packed cols (t*25+v) + 3 zero pad

// ws float offsets
#define WS_STATS 0    // 256 f32: sum[128], sumsq[128]
#define WS_SCALE 256  // 128 f32
#define WS_SHIFT 384  // 128 f32
#define WS_BSUM  512  // 128 f32
#define WS_W2    640  // bf16[128*192]; W2[o][p*64+c]

typedef float f32x4 __attribute__((ext_vector_type(4)));
typedef short s16x8 __attribute__((ext_vector_type(8)));

__device__ __forceinline__ short f2bf(float f) {
    unsigned u = __float_as_uint(f);
    u += 0x7fff + ((u >> 16) & 1);          // RNE
    return (short)(u >> 16);
}

__global__ __launch_bounds__(256) void prep_kernel(const float* __restrict__ W,
                                                   const float* __restrict__ b,
                                                   float* __restrict__ ws) {
    int tid = blockIdx.x * blockDim.x + threadIdx.x;
    if (tid < 256) ws[WS_STATS + tid] = 0.0f;               // zero stats every launch
    if (tid >= 256 && tid < 384) {
        int o = tid - 256;
        ws[WS_BSUM + o] = b[o] + b[COUT + o] + b[2 * COUT + o];
    }
    if (tid < COUT * 192) {                                  // W2[o][k], k = p*64+c
        int o = tid / 192, k = tid % 192;
        int p = k / 64, c = k % 64;
        ((short*)(ws + WS_W2))[tid] = f2bf(W[(p * COUT + o) * CIN + c]);
    }
}

__global__ __launch_bounds__(512, 6) void sgcn_main(const float* __restrict__ x,
                                                    const float* __restrict__ A,
                                                    float* __restrict__ y,
                                                    float* ws) {
    __shared__ __align__(16) short Xs[TTILE * 64 * XSTR];   // 25600 B
    __shared__ __align__(16) short Ats[PP * 32 * XSTR];     // 7680 B (zero-padded)
    __shared__ __align__(16) short Z2s[ZROWS * ZSTR];       // 18432 B
    __shared__ float sstat[256];                            // 1024 B
                                                            // total 52736 B -> 3 blk/CU
    const int tid  = threadIdx.x;
    const int lane = tid & 63;
    const int wave = tid >> 6;
    const int n  = blockIdx.x / NTILES;
    const int t0 = (blockIdx.x % NTILES) * TTILE;
    const int lg = lane >> 4;      // k-block 0..3
    const int li = lane & 15;      // row/col within fragment

    // ---- phase 0: zero At (pads are the K/M padding), Z2 pad rows, sstat ----
    {
        int* az = (int*)Ats;
        #pragma unroll
        for (int i = 0; i < 4; ++i) {
            int idx = tid + i * 512;
            if (idx < PP * 32 * XSTR / 2) az[idx] = 0;
        }
        if (tid < 108) ((int*)(Z2s + 125 * ZSTR))[tid] = 0;   // rows 125..127
        if (tid < 256) sstat[tid] = 0.0f;
    }
    __syncthreads();

    // ---- phase 1: stage X (coalesced strided) + At (transpose) ----
    {
        const float* xb = x + (size_t)n * (CIN * TTOT * VV) + (size_t)t0 * VV;
        #pragma unroll
        for (int it = 0; it < 20; ++it) {                     // 20*512 = 64*5*32
            int i = tid + it * 512;
            int c = i / 160;
            int r2 = i - c * 160;
            int t = r2 >> 5, w = r2 & 31;
            float val = (w < VV) ? xb[c * (TTOT * VV) + t * VV + w] : 0.0f;
            Xs[(t * 64 + c) * XSTR + w] = f2bf(val);
        }
        for (int i = tid; i < PP * VV * VV; i += 512) {
            int v = i % VV, w = (i / VV) % VV, p = i / (VV * VV);
            Ats[(p * 32 + v) * XSTR + w] = f2bf(A[i]);        // At[p][v][w] = A[p][w][v]
        }
    }
    __syncthreads();

    // ---- wave tiling for conv: 4 o-groups x 2 col-groups ----
    const int ow = wave >> 1;          // o0 = ow*32 (2 m-frags)
    const int cw = wave & 1;           // cols cw*64 .. +64 (4 col-frags)
    const int o0 = ow * 32;
    const short* w2 = (const short*)(ws + WS_W2);

    f32x4 acc[2][4];
    #pragma unroll
    for (int mf = 0; mf < 2; ++mf)
        #pragma unroll
        for (int cf = 0; cf < 4; ++cf)
            acc[mf][cf] = (f32x4){0.f, 0.f, 0.f, 0.f};

    for (int p = 0; p < PP; ++p) {
        // prefetch this p's W fragments (global/L2; latency hides under agg)
        s16x8 wf[2][2];
        #pragma unroll
        for (int mf = 0; mf < 2; ++mf)
            #pragma unroll
            for (int ks = 0; ks < 2; ++ks)
                wf[mf][ks] = *(const s16x8*)(w2 + (o0 + mf * 16 + li) * 192
                                                + p * 64 + ks * 32 + lg * 8);

        // aggregation: Z_p^T[col'=t*25+v][c]; 40 frags -> 5 per wave
        #pragma unroll
        for (int q = 0; q < 5; ++q) {
            int f = wave * 5 + q;
            int t = f >> 3, rem = f & 7;
            int vf = rem >> 2, cfr = rem & 3;
            s16x8 af = *(const s16x8*)(&Ats[(p * 32 + vf * 16 + li) * XSTR + lg * 8]);
            s16x8 bf = *(const s16x8*)(&Xs[(t * 64 + cfr * 16 + li) * XSTR + lg * 8]);
            f32x4 z = (f32x4){0.f, 0.f, 0.f, 0.f};
            f32x4 d = __builtin_amdgcn_mfma_f32_16x16x32_bf16(af, bf, z, 0, 0, 0);
            int m0 = vf * 16 + lg * 4;
            int ccol = cfr * 16 + li;
            #pragma unroll
            for (int r = 0; r < 4; ++r) {
                int m = m0 + r;
                if (m < VV) Z2s[(t * VV + m) * ZSTR + ccol] = f2bf(d[r]);
            }
        }
        __syncthreads();

        // conv accumulate: acc += W_p * Z_p (K=64: 2 K-steps)
        #pragma unroll
        for (int cf = 0; cf < 4; ++cf) {
            int col0 = cw * 64 + cf * 16;
            #pragma unroll
            for (int ks = 0; ks < 2; ++ks) {
                s16x8 zf = *(const s16x8*)(&Z2s[(col0 + li) * ZSTR + ks * 32 + lg * 8]);
                #pragma unroll
                for (int mf = 0; mf < 2; ++mf)
                    acc[mf][cf] = __builtin_amdgcn_mfma_f32_16x16x32_bf16(
                        wf[mf][ks], zf, acc[mf][cf], 0, 0, 0);
            }
        }
        __syncthreads();   // protect Z2 before next p's aggregation overwrites
    }

    // ---- epilogue: +bias, store y, per-channel stats ----
    const float* bsum = ws + WS_BSUM;
    #pragma unroll
    for (int mf = 0; mf < 2; ++mf) {
        #pragma unroll
        for (int r = 0; r < 4; ++r) {
            int o = o0 + mf * 16 + lg * 4 + r;
            float bo = bsum[o];
            float s = 0.f, sq = 0.f;
            #pragma unroll
            for (int cf = 0; cf < 4; ++cf) {
                int col = cw * 64 + cf * 16 + li;   // col' = t*25+v
                float val = acc[mf][cf][r] + bo;
                if (col < TTILE * VV) {
                    int t = col / VV;
                    int v = col - t * VV;
                    y[((size_t)(n * COUT + o) * TTOT + (t0 + t)) * VV + v] = val;
                    s += val; sq += val * val;
                }
            }
            #pragma unroll
            for (int m = 1; m < 16; m <<= 1) {
                s  += __shfl_xor(s, m, 64);
                sq += __shfl_xor(sq, m, 64);
            }
            if (li == 0) {
                atomicAdd(&sstat[o], s);
                atomicAdd(&sstat[128 + o], sq);
            }
        }
    }
    __syncthreads();
    if (tid < 256) atomicAdd(&ws[WS_STATS + tid], sstat[tid]);
}

__global__ void finalize_kernel(const float* __restrict__ gamma,
                                const float* __restrict__ beta,
                                float* ws) {
    int o = threadIdx.x;  // 128 threads
    float mean = ws[WS_STATS + o] * (1.0f / CNT);
    float ex2  = ws[WS_STATS + 128 + o] * (1.0f / CNT);
    float var  = ex2 - mean * mean;
    float rstd = rsqrtf(var + 1e-5f);
    float sc = gamma[o] * rstd;
    ws[WS_SCALE + o] = sc;
    ws[WS_SHIFT + o] = beta[o] - mean * sc;
}

__global__ __launch_bounds__(256) void norm_relu_kernel(float* __restrict__ y,
                                                        const float* __restrict__ ws) {
    const int total8 = (NN * COUT * TTOT * VV) / 8;
    const float* scale = ws + WS_SCALE;
    const float* shift = ws + WS_SHIFT;
    for (int i = blockIdx.x * blockDim.x + threadIdx.x; i < total8;
         i += gridDim.x * blockDim.x) {
        size_t base = (size_t)i * 8;
        int row0 = (int)(base / 7500);
        int row1 = (int)((base + 7) / 7500);
        int o0 = row0 & 127, o1 = row1 & 127;
        float s0 = scale[o0], h0 = shift[o0];
        float s1 = scale[o1], h1 = shift[o1];
        size_t bnd = (size_t)(row0 + 1) * 7500;
        float4 a = *(const float4*)(y + base);
        float4 b = *(const float4*)(y + base + 4);
        float vals[8] = {a.x, a.y, a.z, a.w, b.x, b.y, b.z, b.w};
        #pragma unroll
        for (int e = 0; e < 8; ++e) {
            bool first = (base + (size_t)e) < bnd;
            float s = first ? s0 : s1;
            float h = first ? h0 : h1;
            vals[e] = fmaxf(vals[e] * s + h, 0.0f);
        }
        a = make_float4(vals[0], vals[1], vals[2], vals[3]);
        b = make_float4(vals[4], vals[5], vals[6], vals[7]);
        *(float4*)(y + base) = a;
        *(float4*)(y + base + 4) = b;
    }
}

extern "C" void kernel_launch(void* const* d_in, const int* in_sizes, int n_in,
                              void* d_out, int out_size, void* d_ws, size_t ws_size,
                              hipStream_t stream) {
    const float* x     = (const float*)d_in[0];
    const float* A     = (const float*)d_in[1];
    const float* W     = (const float*)d_in[2];
    const float* b     = (const float*)d_in[3];
    const float* gamma = (const float*)d_in[4];
    const float* beta  = (const float*)d_in[5];
    float* y  = (float*)d_out;
    float* ws = (float*)d_ws;   // ~52 KB used

    prep_kernel<<<96, 256, 0, stream>>>(W, b, ws);
    sgcn_main<<<NN * NTILES, 512, 0, stream>>>(x, A, y, ws);
    finalize_kernel<<<1, 128, 0, stream>>>(gamma, beta, ws);
    norm_relu_kernel<<<2048, 256, 0, stream>>>(y, ws);
}

// Round 4
// 148.628 us; speedup vs baseline: 1.2201x; 1.2201x over previous
//
#include <hip/hip_runtime.h>
#include <hip/hip_bf16.h>

#define NN 32
#define CIN 64
#define TTOT 300
#define VV 25
#define PP 3
#define COUT 128
#define TTILE 5
#define NTILES 60
#define CNT 240000.0f

#define XSTR 40      // X/At w-stride in shorts: 80B rows -> 2-way banks, 16B aligned
#define ZSTR 72      // Z2 c-stride in shorts: 144B rows -> ~2-way on b128 reads
#define ZROWS 128    // 125 packed cols (t*25+v) + 3 zero pad

// ws float offsets
#define WS_STATS 0    // 256 f32: sum[128], sumsq[128]
#define WS_SCALE 256  // 128 f32
#define WS_SHIFT 384  // 128 f32
#define WS_BSUM  512  // 128 f32
#define WS_W2    640  // bf16[128*192]; W2[o][p*64+c]

typedef float f32x4 __attribute__((ext_vector_type(4)));
typedef short s16x8 __attribute__((ext_vector_type(8)));

__device__ __forceinline__ short f2bf(float f) {
    unsigned u = __float_as_uint(f);
    u += 0x7fff + ((u >> 16) & 1);          // RNE
    return (short)(u >> 16);
}

__global__ __launch_bounds__(256) void prep_kernel(const float* __restrict__ W,
                                                   const float* __restrict__ b,
                                                   float* __restrict__ ws) {
    int tid = blockIdx.x * blockDim.x + threadIdx.x;
    if (tid < 256) ws[WS_STATS + tid] = 0.0f;               // zero stats every launch
    if (tid >= 256 && tid < 384) {
        int o = tid - 256;
        ws[WS_BSUM + o] = b[o] + b[COUT + o] + b[2 * COUT + o];
    }
    if (tid < COUT * 192) {                                  // W2[o][k], k = p*64+c
        int o = tid / 192, k = tid % 192;
        int p = k / 64, c = k % 64;
        ((short*)(ws + WS_W2))[tid] = f2bf(W[(p * COUT + o) * CIN + c]);
    }
}

// __launch_bounds__(512, 4): VGPR cap 128 (allocator uses ~60, NO spills).
// LDS (52.7 KB) is the binding limit -> 3 blocks/CU = 6 waves/SIMD.
__global__ __launch_bounds__(512, 4) void sgcn_main(const float* __restrict__ x,
                                                    const float* __restrict__ A,
                                                    float* __restrict__ y,
                                                    float* ws) {
    __shared__ __align__(16) short Xs[TTILE * 64 * XSTR];   // 25600 B
    __shared__ __align__(16) short Ats[PP * 32 * XSTR];     // 7680 B (zero-padded)
    __shared__ __align__(16) short Z2s[ZROWS * ZSTR];       // 18432 B
    __shared__ float sstat[256];                            // 1024 B
                                                            // total 52736 B
    const int tid  = threadIdx.x;
    const int lane = tid & 63;
    const int wave = tid >> 6;
    const int n  = blockIdx.x / NTILES;
    const int t0 = (blockIdx.x % NTILES) * TTILE;
    const int lg = lane >> 4;      // k-block 0..3
    const int li = lane & 15;      // row/col within fragment

    // ---- single staging phase: X, At (incl. pads), Z2 pad rows, sstat ----
    {
        const float* xb = x + (size_t)n * (CIN * TTOT * VV) + (size_t)t0 * VV;
        #pragma unroll
        for (int it = 0; it < 20; ++it) {                     // 20*512 = 64*5*32
            int i = tid + it * 512;
            int c = i / 160;
            int r2 = i - c * 160;
            int t = r2 >> 5, w = r2 & 31;
            float val = (w < VV) ? xb[c * (TTOT * VV) + t * VV + w] : 0.0f;
            Xs[(t * 64 + c) * XSTR + w] = f2bf(val);
        }
        // At[p][v][w] = A[p][w][v] for v<25 && w<25, else 0 (pads ARE the K/M pad)
        #pragma unroll
        for (int it = 0; it < 8; ++it) {                      // 8*512 >= 3*32*40
            int i = tid + it * 512;
            if (i < PP * 32 * XSTR) {
                int p = i / (32 * XSTR);
                int r = i - p * (32 * XSTR);
                int v = r / XSTR, w = r - v * XSTR;
                short val = (v < VV && w < VV) ? f2bf(A[p * (VV * VV) + w * VV + v])
                                               : (short)0;
                Ats[i] = val;
            }
        }
        if (tid < 108) ((int*)(Z2s + 125 * ZSTR))[tid] = 0;   // rows 125..127
        if (tid < 256) sstat[tid] = 0.0f;
    }
    __syncthreads();

    // ---- wave tiling for conv: 4 o-groups x 2 col-groups ----
    const int ow = wave >> 1;          // o0 = ow*32 (2 m-frags)
    const int cw = wave & 1;           // cols cw*64 .. +64 (4 col-frags)
    const int o0 = ow * 32;
    const short* w2 = (const short*)(ws + WS_W2);

    f32x4 acc[2][4];
    #pragma unroll
    for (int mf = 0; mf < 2; ++mf)
        #pragma unroll
        for (int cf = 0; cf < 4; ++cf)
            acc[mf][cf] = (f32x4){0.f, 0.f, 0.f, 0.f};

    for (int p = 0; p < PP; ++p) {
        // prefetch this p's W fragments (global/L2; latency hides under agg)
        s16x8 wf[2][2];
        #pragma unroll
        for (int mf = 0; mf < 2; ++mf)
            #pragma unroll
            for (int ks = 0; ks < 2; ++ks)
                wf[mf][ks] = *(const s16x8*)(w2 + (o0 + mf * 16 + li) * 192
                                                + p * 64 + ks * 32 + lg * 8);

        // aggregation: Z_p^T[col'=t*25+v][c]; 40 frags -> 5 per wave
        #pragma unroll
        for (int q = 0; q < 5; ++q) {
            int f = wave * 5 + q;
            int t = f >> 3, rem = f & 7;
            int vf = rem >> 2, cfr = rem & 3;
            s16x8 af = *(const s16x8*)(&Ats[(p * 32 + vf * 16 + li) * XSTR + lg * 8]);
            s16x8 bf = *(const s16x8*)(&Xs[(t * 64 + cfr * 16 + li) * XSTR + lg * 8]);
            f32x4 z = (f32x4){0.f, 0.f, 0.f, 0.f};
            f32x4 d = __builtin_amdgcn_mfma_f32_16x16x32_bf16(af, bf, z, 0, 0, 0);
            int m0 = vf * 16 + lg * 4;
            int ccol = cfr * 16 + li;
            #pragma unroll
            for (int r = 0; r < 4; ++r) {
                int m = m0 + r;
                if (m < VV) Z2s[(t * VV + m) * ZSTR + ccol] = f2bf(d[r]);
            }
        }
        __syncthreads();

        // conv accumulate: acc += W_p * Z_p (K=64: 2 K-steps)
        #pragma unroll
        for (int cf = 0; cf < 4; ++cf) {
            int col0 = cw * 64 + cf * 16;
            #pragma unroll
            for (int ks = 0; ks < 2; ++ks) {
                s16x8 zf = *(const s16x8*)(&Z2s[(col0 + li) * ZSTR + ks * 32 + lg * 8]);
                #pragma unroll
                for (int mf = 0; mf < 2; ++mf)
                    acc[mf][cf] = __builtin_amdgcn_mfma_f32_16x16x32_bf16(
                        wf[mf][ks], zf, acc[mf][cf], 0, 0, 0);
            }
        }
        __syncthreads();   // protect Z2 before next p's aggregation overwrites
    }

    // ---- epilogue: +bias, store y, per-channel stats ----
    const float* bsum = ws + WS_BSUM;
    #pragma unroll
    for (int mf = 0; mf < 2; ++mf) {
        #pragma unroll
        for (int r = 0; r < 4; ++r) {
            int o = o0 + mf * 16 + lg * 4 + r;
            float bo = bsum[o];
            float s = 0.f, sq = 0.f;
            #pragma unroll
            for (int cf = 0; cf < 4; ++cf) {
                int col = cw * 64 + cf * 16 + li;   // col' = t*25+v, contiguous in y
                float val = acc[mf][cf][r] + bo;
                if (col < TTILE * VV) {
                    y[(size_t)(n * COUT + o) * (TTOT * VV) + t0 * VV + col] = val;
                    s += val; sq += val * val;
                }
            }
            #pragma unroll
            for (int m = 1; m < 16; m <<= 1) {
                s  += __shfl_xor(s, m, 64);
                sq += __shfl_xor(sq, m, 64);
            }
            if (li == 0) {
                atomicAdd(&sstat[o], s);
                atomicAdd(&sstat[128 + o], sq);
            }
        }
    }
    __syncthreads();
    if (tid < 256) atomicAdd(&ws[WS_STATS + tid], sstat[tid]);
}

__global__ void finalize_kernel(const float* __restrict__ gamma,
                                const float* __restrict__ beta,
                                float* ws) {
    int o = threadIdx.x;  // 128 threads
    float mean = ws[WS_STATS + o] * (1.0f / CNT);
    float ex2  = ws[WS_STATS + 128 + o] * (1.0f / CNT);
    float var  = ex2 - mean * mean;
    float rstd = rsqrtf(var + 1e-5f);
    float sc = gamma[o] * rstd;
    ws[WS_SCALE + o] = sc;
    ws[WS_SHIFT + o] = beta[o] - mean * sc;
}

__global__ __launch_bounds__(256) void norm_relu_kernel(float* __restrict__ y,
                                                        const float* __restrict__ ws) {
    const int total8 = (NN * COUT * TTOT * VV) / 8;
    const float* scale = ws + WS_SCALE;
    const float* shift = ws + WS_SHIFT;
    for (int i = blockIdx.x * blockDim.x + threadIdx.x; i < total8;
         i += gridDim.x * blockDim.x) {
        size_t base = (size_t)i * 8;
        int row0 = (int)(base / 7500);
        int row1 = (int)((base + 7) / 7500);
        int o0 = row0 & 127, o1 = row1 & 127;
        float s0 = scale[o0], h0 = shift[o0];
        float s1 = scale[o1], h1 = shift[o1];
        size_t bnd = (size_t)(row0 + 1) * 7500;
        float4 a = *(const float4*)(y + base);
        float4 b = *(const float4*)(y + base + 4);
        float vals[8] = {a.x, a.y, a.z, a.w, b.x, b.y, b.z, b.w};
        #pragma unroll
        for (int e = 0; e < 8; ++e) {
            bool first = (base + (size_t)e) < bnd;
            float s = first ? s0 : s1;
            float h = first ? h0 : h1;
            vals[e] = fmaxf(vals[e] * s + h, 0.0f);
        }
        a = make_float4(vals[0], vals[1], vals[2], vals[3]);
        b = make_float4(vals[4], vals[5], vals[6], vals[7]);
        *(float4*)(y + base) = a;
        *(float4*)(y + base + 4) = b;
    }
}

extern "C" void kernel_launch(void* const* d_in, const int* in_sizes, int n_in,
                              void* d_out, int out_size, void* d_ws, size_t ws_size,
                              hipStream_t stream) {
    const float* x     = (const float*)d_in[0];
    const float* A     = (const float*)d_in[1];
    const float* W     = (const float*)d_in[2];
    const float* b     = (const float*)d_in[3];
    const float* gamma = (const float*)d_in[4];
    const float* beta  = (const float*)d_in[5];
    float* y  = (float*)d_out;
    float* ws = (float*)d_ws;   // ~52 KB used

    prep_kernel<<<96, 256, 0, stream>>>(W, b, ws);
    sgcn_main<<<NN * NTILES, 512, 0, stream>>>(x, A, y, ws);
    finalize_kernel<<<1, 128, 0, stream>>>(gamma, beta, ws);
    norm_relu_kernel<<<2048, 256, 0, stream>>>(y, ws);
}